// Round 4
// baseline (398.530 us; speedup 1.0000x reference)
//
#include <hip/hip_runtime.h>
#include <hip/hip_bf16.h>

#define B_ 64
#define N_ 2048
#define E_ 16384
#define F_ 32
#define H_ 64
#define K_ 8
#define C_ 16
#define G_ 64
#define CK 128        // C_*K_
#define CAP 120       // linc row nnz capacity (Binomial mean 64, sd 8 -> mean+7sd)
#define RCAP 72       // rinc row nnz capacity (mean 8, sd 2.8 -> mean+22sd)
#define YLD 136       // bf16 row stride for s_y (pad 8: 16B-aligned rows)
#define BC 1024       // B_*C_

typedef __attribute__((ext_vector_type(8))) short bf16x8;
typedef __attribute__((ext_vector_type(8))) unsigned short u16x8;
typedef __attribute__((ext_vector_type(4))) float f32x4;

__device__ inline float bf2f(unsigned short u) {
  union { unsigned int i; float f; } v; v.i = ((unsigned int)u) << 16; return v.f;
}
__device__ inline unsigned short f2bf(float f) {
  union { float f; unsigned int i; } v; v.f = f;
  unsigned int x = v.i;
  return (unsigned short)((x + 0x7fffu + ((x >> 16) & 1u)) >> 16);
}

// ---------------- Kernel X: transpose x[b,n,c] -> x_t[n][b*16+c] (bf16) ----------------
__global__ __launch_bounds__(256) void xpose_k(
    const float* __restrict__ x, unsigned short* __restrict__ x_t) {
  int t = threadIdx.x;
  int n = blockIdx.x;
  int b = t >> 2, c0 = (t & 3) * 4;
  float4 xv = *(const float4*)(x + (size_t)b*(N_*C_) + (size_t)n*C_ + c0);
  ushort4 o;
  o.x = f2bf(xv.x); o.y = f2bf(xv.y); o.z = f2bf(xv.z); o.w = f2bf(xv.w);
  *(ushort4*)&x_t[(size_t)n*BC + 4*t] = o;
}

// ---------------- Kernel A: edge MLP -> w[E,K] ----------------
__global__ __launch_bounds__(256) void edge_mlp_k(
    const float* __restrict__ ef, const float* __restrict__ w1,
    const float* __restrict__ b1, const float* __restrict__ w2,
    const float* __restrict__ b2, float* __restrict__ w_out) {
  __shared__ float s_w1[H_*F_];
  __shared__ float s_w2[K_*H_];
  __shared__ float s_b1[H_];
  __shared__ float s_b2[K_];
  int t = threadIdx.x;
  for (int i = t; i < H_*F_; i += 256) s_w1[i] = w1[i];
  for (int i = t; i < K_*H_; i += 256) s_w2[i] = w2[i];
  if (t < H_) s_b1[t] = b1[t];
  if (t < K_) s_b2[t] = b2[t];
  __syncthreads();
  int e = blockIdx.x*256 + t;
  float efr[F_];
  const float4* efp = (const float4*)(ef + (size_t)e*F_);
  #pragma unroll
  for (int f4 = 0; f4 < F_/4; f4++) {
    float4 v = efp[f4];
    efr[f4*4+0]=v.x; efr[f4*4+1]=v.y; efr[f4*4+2]=v.z; efr[f4*4+3]=v.w;
  }
  float acc[K_];
  #pragma unroll
  for (int k = 0; k < K_; k++) acc[k] = s_b2[k];
  #pragma unroll 4
  for (int h = 0; h < H_; h++) {
    float hv = s_b1[h];
    #pragma unroll
    for (int f = 0; f < F_; f++) hv = fmaf(efr[f], s_w1[h*F_+f], hv);
    hv = fmaxf(hv, 0.f);
    #pragma unroll
    for (int k = 0; k < K_; k++) acc[k] = fmaf(hv, s_w2[k*H_+h], acc[k]);
  }
  #pragma unroll
  for (int k = 0; k < K_; k++) w_out[(size_t)e*K_ + k] = acc[k];
}

// ------- Kernel B: z[e][bc] (bf16) = sum_{n: rinc[e,n]!=0} x_t[n][bc] -------
// One WAVE per edge (4 edges/block); no block-wide syncs; wave-private LDS lists.
__global__ __launch_bounds__(256) void gather_z_k(
    const float* __restrict__ rinc, const unsigned short* __restrict__ x_t,
    unsigned short* __restrict__ z) {
  __shared__ int s_idx[4][RCAP];
  __shared__ int s_cnt[4];
  int t = threadIdx.x, wv = t >> 6, lane = t & 63;
  int e = blockIdx.x * 4 + wv;
  if (lane == 0) s_cnt[wv] = 0;
  const float4* row = (const float4*)(rinc + (size_t)e*N_);
  #pragma unroll
  for (int j = 0; j < N_/4/64; j++) {        // 8 float4 per lane
    int i = lane + 64*j;
    float4 v = row[i];
    if (v.x != 0.f) { int p = atomicAdd(&s_cnt[wv],1); if (p<RCAP) s_idx[wv][p]=i*4+0; }
    if (v.y != 0.f) { int p = atomicAdd(&s_cnt[wv],1); if (p<RCAP) s_idx[wv][p]=i*4+1; }
    if (v.z != 0.f) { int p = atomicAdd(&s_cnt[wv],1); if (p<RCAP) s_idx[wv][p]=i*4+2; }
    if (v.w != 0.f) { int p = atomicAdd(&s_cnt[wv],1); if (p<RCAP) s_idx[wv][p]=i*4+3; }
  }
  // wave-lockstep: all lanes' LDS atomics precede this read in program order
  int cnt = min(s_cnt[wv], RCAP);
  // lane owns 16 consecutive bc -> two 16B loads per nnz (wave covers full 2KB row)
  const unsigned short* xb = x_t + 16*lane;
  float acc[16];
  #pragma unroll
  for (int k = 0; k < 16; k++) acc[k] = 0.f;
  for (int i = 0; i < cnt; i++) {
    int n = s_idx[wv][i];
    u16x8 a0 = *(const u16x8*)(xb + (size_t)n*BC);
    u16x8 a1 = *(const u16x8*)(xb + (size_t)n*BC + 8);
    #pragma unroll
    for (int k = 0; k < 8; k++) { acc[k] += bf2f(a0[k]); acc[8+k] += bf2f(a1[k]); }
  }
  u16x8 o0, o1;
  #pragma unroll
  for (int k = 0; k < 8; k++) { o0[k] = f2bf(acc[k]); o1[k] = f2bf(acc[8+k]); }
  unsigned short* zp = z + (size_t)e*BC + 16*lane;
  *(u16x8*)zp = o0;
  *(u16x8*)(zp + 8) = o1;
}

// ------- Kernel C: per-node y accumulate (VALU) + MFMA output GEMM -------
// LDS < 20KB -> 8 blocks/CU (32 waves, 100% occupancy target).
__global__ __launch_bounds__(256, 8) void node_out_k(
    const float* __restrict__ linc, const unsigned short* __restrict__ z,
    const float* __restrict__ w, const float* __restrict__ gcw,
    const float* __restrict__ gcb, float* __restrict__ out) {
  __shared__ unsigned short s_y[B_*YLD];        // y as bf16, [b][ck], 17.4 KB
  __shared__ unsigned short s_wb[CAP*K_];       // per-edge weights bf16, 1.9 KB
  __shared__ float s_gcb[G_];
  __shared__ int   s_idx[CAP];
  __shared__ int   s_cnt;
  int t = threadIdx.x;
  int n = blockIdx.x;
  if (t == 0) s_cnt = 0;
  if (t < G_) s_gcb[t] = gcb[t];
  __syncthreads();

  // scan linc row n (64 KB, float4-coalesced)
  const float4* row = (const float4*)(linc + (size_t)n*E_);
  #pragma unroll
  for (int j = 0; j < E_/4/256; j++) {        // 16 float4 per thread
    int i = t + 256*j;
    float4 v = row[i];
    if (v.x != 0.f) { int p = atomicAdd(&s_cnt,1); if (p<CAP) s_idx[p]=i*4+0; }
    if (v.y != 0.f) { int p = atomicAdd(&s_cnt,1); if (p<CAP) s_idx[p]=i*4+1; }
    if (v.z != 0.f) { int p = atomicAdd(&s_cnt,1); if (p<CAP) s_idx[p]=i*4+2; }
    if (v.w != 0.f) { int p = atomicAdd(&s_cnt,1); if (p<CAP) s_idx[p]=i*4+3; }
  }
  __syncthreads();
  int cnt = min(s_cnt, CAP);
  for (int i = t; i < cnt*K_; i += 256) {
    int ii = i >> 3, k = i & 7;
    s_wb[i] = f2bf(w[(size_t)s_idx[ii]*K_ + k]);
  }
  __syncthreads();

  // stage 1: y accumulate. Thread owns bc = 4t..4t+3 (b = t>>2, c0 = (t&3)*4), all 8 k.
  float acc[4][K_];
  #pragma unroll
  for (int j = 0; j < 4; j++)
    #pragma unroll
    for (int k = 0; k < K_; k++) acc[j][k] = 0.f;
  const unsigned short* zt = z + 4*t;
  for (int i = 0; i < cnt; i++) {
    int e = s_idx[i];
    u16x8 wv8 = *(const u16x8*)&s_wb[i*K_];
    float we[K_];
    #pragma unroll
    for (int k = 0; k < K_; k++) we[k] = bf2f(wv8[k]);
    ushort4 zu = *(const ushort4*)(zt + (size_t)e*BC);
    float zv[4] = {bf2f(zu.x), bf2f(zu.y), bf2f(zu.z), bf2f(zu.w)};
    #pragma unroll
    for (int j = 0; j < 4; j++)
      #pragma unroll
      for (int k = 0; k < K_; k++) acc[j][k] = fmaf(zv[j], we[k], acc[j][k]);
  }
  // spill y -> LDS bf16: thread covers 32 consecutive ck at row b
  {
    int b = t >> 2, ckb = (t & 3) * 32;
    #pragma unroll
    for (int j = 0; j < 4; j++) {
      ushort4 lo, hi;
      lo.x = f2bf(acc[j][0]); lo.y = f2bf(acc[j][1]); lo.z = f2bf(acc[j][2]); lo.w = f2bf(acc[j][3]);
      hi.x = f2bf(acc[j][4]); hi.y = f2bf(acc[j][5]); hi.z = f2bf(acc[j][6]); hi.w = f2bf(acc[j][7]);
      *(ushort4*)&s_y[b*YLD + ckb + 8*j]     = lo;
      *(ushort4*)&s_y[b*YLD + ckb + 8*j + 4] = hi;
    }
  }
  __syncthreads();

  // stage 2: out[b, n, g] = relu(y[b,:] . gcw[g,:] + gcb[g]) via MFMA 16x16x32 bf16.
  // B-frags loaded straight from global gcw (L2-resident, 32KB) -> no LDS staging.
  {
    int wv = t >> 6, lane = t & 63;
    int m = lane & 15, q = lane >> 4;
    f32x4 cf0 = {0.f,0.f,0.f,0.f}, cf1 = cf0, cf2 = cf0, cf3 = cf0;
    #pragma unroll
    for (int ks = 0; ks < 4; ks++) {
      bf16x8 a = *(const bf16x8*)&s_y[(16*wv + m)*YLD + 32*ks + 8*q];
      bf16x8 bf[4];
      #pragma unroll
      for (int gf = 0; gf < 4; gf++) {
        const float* gp = gcw + (size_t)(16*gf + m)*CK + 32*ks + 8*q;
        float4 g0 = *(const float4*)gp;
        float4 g1 = *(const float4*)(gp + 4);
        bf[gf][0]=(short)f2bf(g0.x); bf[gf][1]=(short)f2bf(g0.y);
        bf[gf][2]=(short)f2bf(g0.z); bf[gf][3]=(short)f2bf(g0.w);
        bf[gf][4]=(short)f2bf(g1.x); bf[gf][5]=(short)f2bf(g1.y);
        bf[gf][6]=(short)f2bf(g1.z); bf[gf][7]=(short)f2bf(g1.w);
      }
      cf0 = __builtin_amdgcn_mfma_f32_16x16x32_bf16(a, bf[0], cf0, 0, 0, 0);
      cf1 = __builtin_amdgcn_mfma_f32_16x16x32_bf16(a, bf[1], cf1, 0, 0, 0);
      cf2 = __builtin_amdgcn_mfma_f32_16x16x32_bf16(a, bf[2], cf2, 0, 0, 0);
      cf3 = __builtin_amdgcn_mfma_f32_16x16x32_bf16(a, bf[3], cf3, 0, 0, 0);
    }
    float* ob = out + (size_t)n*G_;
    #pragma unroll
    for (int r = 0; r < 4; r++) {
      int b = 16*wv + 4*q + r;
      float* op = ob + (size_t)b*(N_*G_);
      float v0 = fmaxf(cf0[r] + s_gcb[m],      0.f);
      float v1 = fmaxf(cf1[r] + s_gcb[16 + m], 0.f);
      float v2 = fmaxf(cf2[r] + s_gcb[32 + m], 0.f);
      float v3 = fmaxf(cf3[r] + s_gcb[48 + m], 0.f);
      op[m]      = v0;
      op[16 + m] = v1;
      op[32 + m] = v2;
      op[48 + m] = v3;
    }
  }
}

extern "C" void kernel_launch(void* const* d_in, const int* in_sizes, int n_in,
                              void* d_out, int out_size, void* d_ws, size_t ws_size,
                              hipStream_t stream) {
  const float* x    = (const float*)d_in[0];
  const float* linc = (const float*)d_in[1];
  const float* rinc = (const float*)d_in[2];
  const float* ef   = (const float*)d_in[3];
  const float* w1   = (const float*)d_in[4];
  const float* b1   = (const float*)d_in[5];
  const float* w2   = (const float*)d_in[6];
  const float* b2   = (const float*)d_in[7];
  const float* gcw  = (const float*)d_in[8];
  const float* gcb  = (const float*)d_in[9];
  float* out = (float*)d_out;

  char* ws = (char*)d_ws;
  float* w_e          = (float*)ws;                 ws += (size_t)E_*K_*sizeof(float);     // 512 KB
  unsigned short* z   = (unsigned short*)ws;        ws += (size_t)E_*BC*sizeof(short);     // 33.5 MB
  unsigned short* x_t = (unsigned short*)ws;        ws += (size_t)N_*BC*sizeof(short);     // 4.2 MB

  xpose_k<<<N_, 256, 0, stream>>>(x, x_t);
  edge_mlp_k<<<E_/256, 256, 0, stream>>>(ef, w1, b1, w2, b2, w_e);
  gather_z_k<<<E_/4, 256, 0, stream>>>(rinc, x_t, z);
  node_out_k<<<N_, 256, 0, stream>>>(linc, z, w_e, gcw, gcb, out);
}

// Round 6
// 369.948 us; speedup vs baseline: 1.0773x; 1.0773x over previous
//
#include <hip/hip_runtime.h>
#include <hip/hip_bf16.h>

#define B_ 64
#define N_ 2048
#define E_ 16384
#define F_ 32
#define H_ 64
#define K_ 8
#define C_ 16
#define G_ 64
#define CK 128        // C_*K_
#define CAP 120       // linc row nnz capacity (Binomial mean 64, sd 8 -> mean+7sd)
#define RCAP 72       // rinc row nnz capacity (mean 8, sd 2.8 -> mean+22sd)
#define YLD 136       // bf16 row stride for s_y (pad 8: 16B-aligned rows)
#define BC 1024       // B_*C_

typedef __attribute__((ext_vector_type(8))) short bf16x8;
typedef __attribute__((ext_vector_type(8))) unsigned short u16x8;
typedef __attribute__((ext_vector_type(4))) float f32x4;

__device__ inline float bf2f(unsigned short u) {
  union { unsigned int i; float f; } v; v.i = ((unsigned int)u) << 16; return v.f;
}
__device__ inline unsigned short f2bf(float f) {
  union { float f; unsigned int i; } v; v.f = f;
  unsigned int x = v.i;
  return (unsigned short)((x + 0x7fffu + ((x >> 16) & 1u)) >> 16);
}

// ---- Kernel X: transpose x[b,n,c] -> x_t[n][b*16+c] (bf16); last block converts gcw->bf16 ----
__global__ __launch_bounds__(256) void xpose_k(
    const float* __restrict__ x, const float* __restrict__ gcw,
    unsigned short* __restrict__ x_t, unsigned short* __restrict__ gcw_bf) {
  int t = threadIdx.x;
  if (blockIdx.x == N_) {
    for (int i = t; i < G_*CK; i += 256) gcw_bf[i] = f2bf(gcw[i]);
    return;
  }
  int n = blockIdx.x;
  int b = t >> 2, c0 = (t & 3) * 4;
  float4 xv = *(const float4*)(x + (size_t)b*(N_*C_) + (size_t)n*C_ + c0);
  ushort4 o;
  o.x = f2bf(xv.x); o.y = f2bf(xv.y); o.z = f2bf(xv.z); o.w = f2bf(xv.w);
  *(ushort4*)&x_t[(size_t)n*BC + 4*t] = o;
}

// ---------------- Kernel A: edge MLP -> w[E,K] ----------------
__global__ __launch_bounds__(256) void edge_mlp_k(
    const float* __restrict__ ef, const float* __restrict__ w1,
    const float* __restrict__ b1, const float* __restrict__ w2,
    const float* __restrict__ b2, float* __restrict__ w_out) {
  __shared__ float s_w1[H_*F_];
  __shared__ float s_w2[K_*H_];
  __shared__ float s_b1[H_];
  __shared__ float s_b2[K_];
  int t = threadIdx.x;
  for (int i = t; i < H_*F_; i += 256) s_w1[i] = w1[i];
  for (int i = t; i < K_*H_; i += 256) s_w2[i] = w2[i];
  if (t < H_) s_b1[t] = b1[t];
  if (t < K_) s_b2[t] = b2[t];
  __syncthreads();
  int e = blockIdx.x*256 + t;
  float efr[F_];
  const float4* efp = (const float4*)(ef + (size_t)e*F_);
  #pragma unroll
  for (int f4 = 0; f4 < F_/4; f4++) {
    float4 v = efp[f4];
    efr[f4*4+0]=v.x; efr[f4*4+1]=v.y; efr[f4*4+2]=v.z; efr[f4*4+3]=v.w;
  }
  float acc[K_];
  #pragma unroll
  for (int k = 0; k < K_; k++) acc[k] = s_b2[k];
  #pragma unroll 4
  for (int h = 0; h < H_; h++) {
    float hv = s_b1[h];
    #pragma unroll
    for (int f = 0; f < F_; f++) hv = fmaf(efr[f], s_w1[h*F_+f], hv);
    hv = fmaxf(hv, 0.f);
    #pragma unroll
    for (int k = 0; k < K_; k++) acc[k] = fmaf(hv, s_w2[k*H_+h], acc[k]);
  }
  #pragma unroll
  for (int k = 0; k < K_; k++) w_out[(size_t)e*K_ + k] = acc[k];
}

// ------- Kernel B: z[e][bc] (bf16) = sum_{n: rinc[e,n]!=0} x_t[n][bc] -------
// One WAVE per edge (4 edges/block); no block-wide syncs; wave-private LDS lists.
__global__ __launch_bounds__(256) void gather_z_k(
    const float* __restrict__ rinc, const unsigned short* __restrict__ x_t,
    unsigned short* __restrict__ z) {
  __shared__ int s_idx[4][RCAP];
  __shared__ int s_cnt[4];
  int t = threadIdx.x, wv = t >> 6, lane = t & 63;
  int e = blockIdx.x * 4 + wv;
  if (lane == 0) s_cnt[wv] = 0;
  const f32x4* row = (const f32x4*)(rinc + (size_t)e*N_);
  #pragma unroll
  for (int j = 0; j < N_/4/64; j++) {        // 8 float4 per lane, streaming (no reuse)
    int i = lane + 64*j;
    f32x4 v = __builtin_nontemporal_load(row + i);
    if (v.x != 0.f) { int p = atomicAdd(&s_cnt[wv],1); if (p<RCAP) s_idx[wv][p]=i*4+0; }
    if (v.y != 0.f) { int p = atomicAdd(&s_cnt[wv],1); if (p<RCAP) s_idx[wv][p]=i*4+1; }
    if (v.z != 0.f) { int p = atomicAdd(&s_cnt[wv],1); if (p<RCAP) s_idx[wv][p]=i*4+2; }
    if (v.w != 0.f) { int p = atomicAdd(&s_cnt[wv],1); if (p<RCAP) s_idx[wv][p]=i*4+3; }
  }
  // wave-lockstep: all lanes' LDS atomics precede this read in program order
  int cnt = min(s_cnt[wv], RCAP);
  // lane owns 16 consecutive bc -> two 16B loads per nnz (wave covers full 2KB row)
  const unsigned short* xb = x_t + 16*lane;
  float acc[16];
  #pragma unroll
  for (int k = 0; k < 16; k++) acc[k] = 0.f;
  for (int i = 0; i < cnt; i++) {
    int n = s_idx[wv][i];
    u16x8 a0 = *(const u16x8*)(xb + (size_t)n*BC);
    u16x8 a1 = *(const u16x8*)(xb + (size_t)n*BC + 8);
    #pragma unroll
    for (int k = 0; k < 8; k++) { acc[k] += bf2f(a0[k]); acc[8+k] += bf2f(a1[k]); }
  }
  u16x8 o0, o1;
  #pragma unroll
  for (int k = 0; k < 8; k++) { o0[k] = f2bf(acc[k]); o1[k] = f2bf(acc[8+k]); }
  unsigned short* zp = z + (size_t)e*BC + 16*lane;
  *(u16x8*)zp = o0;
  *(u16x8*)(zp + 8) = o1;
}

// ------- Kernel C: per-node y accumulate (VALU) + MFMA output GEMM -------
// LDS ~20KB (7 blocks/CU); VGPR bound 6 waves/EU (no spills) -> ~6 blocks/CU.
__global__ __launch_bounds__(256, 6) void node_out_k(
    const float* __restrict__ linc, const unsigned short* __restrict__ z,
    const float* __restrict__ w, const unsigned short* __restrict__ gcw_bf,
    const float* __restrict__ gcb, float* __restrict__ out) {
  __shared__ unsigned short s_y[B_*YLD];        // y as bf16, [b][ck], 17.4 KB
  __shared__ unsigned short s_wb[CAP*K_];       // per-edge weights bf16, 1.9 KB
  __shared__ float s_gcb[G_];
  __shared__ int   s_idx[CAP];
  __shared__ int   s_cnt;
  int t = threadIdx.x;
  int n = blockIdx.x;
  if (t == 0) s_cnt = 0;
  if (t < G_) s_gcb[t] = gcb[t];
  __syncthreads();

  // scan linc row n (64 KB, float4-coalesced, streaming -> non-temporal)
  const f32x4* row = (const f32x4*)(linc + (size_t)n*E_);
  #pragma unroll
  for (int j = 0; j < E_/4/256; j++) {        // 16 float4 per thread
    int i = t + 256*j;
    f32x4 v = __builtin_nontemporal_load(row + i);
    if (v.x != 0.f) { int p = atomicAdd(&s_cnt,1); if (p<CAP) s_idx[p]=i*4+0; }
    if (v.y != 0.f) { int p = atomicAdd(&s_cnt,1); if (p<CAP) s_idx[p]=i*4+1; }
    if (v.z != 0.f) { int p = atomicAdd(&s_cnt,1); if (p<CAP) s_idx[p]=i*4+2; }
    if (v.w != 0.f) { int p = atomicAdd(&s_cnt,1); if (p<CAP) s_idx[p]=i*4+3; }
  }
  __syncthreads();
  int cnt = min(s_cnt, CAP);
  for (int i = t; i < cnt*K_; i += 256) {
    int ii = i >> 3, k = i & 7;
    s_wb[i] = f2bf(w[(size_t)s_idx[ii]*K_ + k]);
  }
  __syncthreads();

  // stage 1: y accumulate. Thread owns bc = 4t..4t+3 (b = t>>2, c0 = (t&3)*4), all 8 k.
  float acc[4][K_];
  #pragma unroll
  for (int j = 0; j < 4; j++)
    #pragma unroll
    for (int k = 0; k < K_; k++) acc[j][k] = 0.f;
  const unsigned short* zt = z + 4*t;
  for (int i = 0; i < cnt; i++) {
    int e = s_idx[i];
    u16x8 wv8 = *(const u16x8*)&s_wb[i*K_];
    float we[K_];
    #pragma unroll
    for (int k = 0; k < K_; k++) we[k] = bf2f(wv8[k]);
    ushort4 zu = *(const ushort4*)(zt + (size_t)e*BC);
    float zv[4] = {bf2f(zu.x), bf2f(zu.y), bf2f(zu.z), bf2f(zu.w)};
    #pragma unroll
    for (int j = 0; j < 4; j++)
      #pragma unroll
      for (int k = 0; k < K_; k++) acc[j][k] = fmaf(zv[j], we[k], acc[j][k]);
  }
  // spill y -> LDS bf16: thread covers 32 consecutive ck at row b
  {
    int b = t >> 2, ckb = (t & 3) * 32;
    #pragma unroll
    for (int j = 0; j < 4; j++) {
      ushort4 lo, hi;
      lo.x = f2bf(acc[j][0]); lo.y = f2bf(acc[j][1]); lo.z = f2bf(acc[j][2]); lo.w = f2bf(acc[j][3]);
      hi.x = f2bf(acc[j][4]); hi.y = f2bf(acc[j][5]); hi.z = f2bf(acc[j][6]); hi.w = f2bf(acc[j][7]);
      *(ushort4*)&s_y[b*YLD + ckb + 8*j]     = lo;
      *(ushort4*)&s_y[b*YLD + ckb + 8*j + 4] = hi;
    }
  }
  __syncthreads();

  // stage 2: out[b, n, g] = relu(y[b,:] . gcw[g,:] + gcb[g]) via MFMA 16x16x32 bf16.
  // B-frags: direct bf16x8 loads from pre-converted gcw_bf (16KB, L1-resident).
  {
    int wv = t >> 6, lane = t & 63;
    int m = lane & 15, q = lane >> 4;
    f32x4 cf0 = {0.f,0.f,0.f,0.f}, cf1 = cf0, cf2 = cf0, cf3 = cf0;
    #pragma unroll
    for (int ks = 0; ks < 4; ks++) {
      bf16x8 a = *(const bf16x8*)&s_y[(16*wv + m)*YLD + 32*ks + 8*q];
      bf16x8 b0 = *(const bf16x8*)&gcw_bf[(size_t)(m     )*CK + 32*ks + 8*q];
      bf16x8 b1 = *(const bf16x8*)&gcw_bf[(size_t)(16 + m)*CK + 32*ks + 8*q];
      bf16x8 b2 = *(const bf16x8*)&gcw_bf[(size_t)(32 + m)*CK + 32*ks + 8*q];
      bf16x8 b3 = *(const bf16x8*)&gcw_bf[(size_t)(48 + m)*CK + 32*ks + 8*q];
      cf0 = __builtin_amdgcn_mfma_f32_16x16x32_bf16(a, b0, cf0, 0, 0, 0);
      cf1 = __builtin_amdgcn_mfma_f32_16x16x32_bf16(a, b1, cf1, 0, 0, 0);
      cf2 = __builtin_amdgcn_mfma_f32_16x16x32_bf16(a, b2, cf2, 0, 0, 0);
      cf3 = __builtin_amdgcn_mfma_f32_16x16x32_bf16(a, b3, cf3, 0, 0, 0);
    }
    float* ob = out + (size_t)n*G_;
    #pragma unroll
    for (int r = 0; r < 4; r++) {
      int b = 16*wv + 4*q + r;
      float* op = ob + (size_t)b*(N_*G_);
      float v0 = fmaxf(cf0[r] + s_gcb[m],      0.f);
      float v1 = fmaxf(cf1[r] + s_gcb[16 + m], 0.f);
      float v2 = fmaxf(cf2[r] + s_gcb[32 + m], 0.f);
      float v3 = fmaxf(cf3[r] + s_gcb[48 + m], 0.f);
      op[m]      = v0;
      op[16 + m] = v1;
      op[32 + m] = v2;
      op[48 + m] = v3;
    }
  }
}

extern "C" void kernel_launch(void* const* d_in, const int* in_sizes, int n_in,
                              void* d_out, int out_size, void* d_ws, size_t ws_size,
                              hipStream_t stream) {
  const float* x    = (const float*)d_in[0];
  const float* linc = (const float*)d_in[1];
  const float* rinc = (const float*)d_in[2];
  const float* ef   = (const float*)d_in[3];
  const float* w1   = (const float*)d_in[4];
  const float* b1   = (const float*)d_in[5];
  const float* w2   = (const float*)d_in[6];
  const float* b2   = (const float*)d_in[7];
  const float* gcw  = (const float*)d_in[8];
  const float* gcb  = (const float*)d_in[9];
  float* out = (float*)d_out;

  char* ws = (char*)d_ws;
  float* w_e             = (float*)ws;            ws += (size_t)E_*K_*sizeof(float);   // 512 KB
  unsigned short* z      = (unsigned short*)ws;   ws += (size_t)E_*BC*sizeof(short);   // 33.5 MB
  unsigned short* x_t    = (unsigned short*)ws;   ws += (size_t)N_*BC*sizeof(short);   // 4.2 MB
  unsigned short* gcw_bf = (unsigned short*)ws;   ws += (size_t)G_*CK*sizeof(short);   // 16 KB

  xpose_k<<<N_+1, 256, 0, stream>>>(x, gcw, x_t, gcw_bf);
  edge_mlp_k<<<E_/256, 256, 0, stream>>>(ef, w1, b1, w2, b2, w_e);
  gather_z_k<<<E_/4, 256, 0, stream>>>(rinc, x_t, z);
  node_out_k<<<N_, 256, 0, stream>>>(linc, z, w_e, gcw_bf, gcb, out);
}